// Round 1
// baseline (235.582 us; speedup 1.0000x reference)
//
#include <hip/hip_runtime.h>
#include <cstdint>
#include <cstddef>

#define T_TOK 8192
#define MDIM  4096
#define NEXP  64
#define CAP   128
#define KSPLIT 4
#define KCHUNK (MDIM / KSPLIT)   // 1024

// ---------------------------------------------------------------------------
// GEMM: logits partials.  part[s][t][e] = sum_{k in split s} x[t][k]*wg[e][k]
// BM=64 tokens, BN=64 experts (all), BK=32, 256 threads, 4x4 microtile.
// ---------------------------------------------------------------------------
__global__ __launch_bounds__(256) void gemm_partial(
    const float* __restrict__ x, const float* __restrict__ wg,
    float* __restrict__ part) {
  __shared__ __align__(16) float As[32][64];  // [k][m]
  __shared__ __align__(16) float Bs[32][64];  // [k][e]
  const int tid = threadIdx.x;
  const int t0  = blockIdx.x * 64;
  const int ks  = blockIdx.y;
  const int tx  = tid & 15;        // expert group
  const int ty  = tid >> 4;        // token group
  const int r   = tid >> 2;        // staging row (0..63)
  const int q   = tid & 3;         // staging col group

  float acc[4][4] = {};

  const float* xrow = x  + (size_t)(t0 + r) * MDIM;
  const float* wrow = wg + (size_t)r * MDIM;

  const int kend = ks * KCHUNK + KCHUNK;
  for (int k0 = ks * KCHUNK; k0 < kend; k0 += 32) {
    const float4 a0 = *(const float4*)(xrow + k0 + 8 * q);
    const float4 a1 = *(const float4*)(xrow + k0 + 8 * q + 4);
    const float4 b0 = *(const float4*)(wrow + k0 + 8 * q);
    const float4 b1 = *(const float4*)(wrow + k0 + 8 * q + 4);
    __syncthreads();   // WAR: previous iter's reads done before overwrite
    As[8*q+0][r] = a0.x; As[8*q+1][r] = a0.y; As[8*q+2][r] = a0.z; As[8*q+3][r] = a0.w;
    As[8*q+4][r] = a1.x; As[8*q+5][r] = a1.y; As[8*q+6][r] = a1.z; As[8*q+7][r] = a1.w;
    Bs[8*q+0][r] = b0.x; Bs[8*q+1][r] = b0.y; Bs[8*q+2][r] = b0.z; Bs[8*q+3][r] = b0.w;
    Bs[8*q+4][r] = b1.x; Bs[8*q+5][r] = b1.y; Bs[8*q+6][r] = b1.z; Bs[8*q+7][r] = b1.w;
    __syncthreads();
#pragma unroll
    for (int kk = 0; kk < 32; ++kk) {
      const float4 av = *(const float4*)&As[kk][ty * 4];
      const float4 bv = *(const float4*)&Bs[kk][tx * 4];
      acc[0][0] += av.x * bv.x; acc[0][1] += av.x * bv.y;
      acc[0][2] += av.x * bv.z; acc[0][3] += av.x * bv.w;
      acc[1][0] += av.y * bv.x; acc[1][1] += av.y * bv.y;
      acc[1][2] += av.y * bv.z; acc[1][3] += av.y * bv.w;
      acc[2][0] += av.z * bv.x; acc[2][1] += av.z * bv.y;
      acc[2][2] += av.z * bv.z; acc[2][3] += av.z * bv.w;
      acc[3][0] += av.w * bv.x; acc[3][1] += av.w * bv.y;
      acc[3][2] += av.w * bv.z; acc[3][3] += av.w * bv.w;
    }
  }
#pragma unroll
  for (int i = 0; i < 4; ++i) {
    float4 v = make_float4(acc[i][0], acc[i][1], acc[i][2], acc[i][3]);
    *(float4*)(part + ((size_t)ks * T_TOK + t0 + ty * 4 + i) * NEXP + tx * 4) = v;
  }
}

// ---------------------------------------------------------------------------
// Reduce split-K, per-row softmax + argmax (tie -> min index), per-expert
// gate-sum and argmax-count accumulation.  One wave (64 lanes) per token.
// ---------------------------------------------------------------------------
__global__ __launch_bounds__(256) void softmax_stats(
    const float* __restrict__ part, int* __restrict__ idx,
    float* __restrict__ gval, float* __restrict__ esum,
    int* __restrict__ ecnt) {
  const int tid  = threadIdx.x;
  const int wid  = tid >> 6;
  const int lane = tid & 63;
  const int t    = blockIdx.x * 4 + wid;

  float v = 0.f;
#pragma unroll
  for (int s = 0; s < KSPLIT; ++s)
    v += part[((size_t)s * T_TOK + t) * NEXP + lane];

  // wave argmax (value, min-index on ties)
  float m = v; int mi = lane;
#pragma unroll
  for (int d = 32; d >= 1; d >>= 1) {
    float om = __shfl_xor(m, d);
    int   oi = __shfl_xor(mi, d);
    if (om > m || (om == m && oi < mi)) { m = om; mi = oi; }
  }
  const float e = expf(v - m);
  float denom = e;
#pragma unroll
  for (int d = 32; d >= 1; d >>= 1) denom += __shfl_xor(denom, d);
  const float g = e / denom;

  __shared__ float sg[4][64];
  __shared__ int   scnt[64];
  if (tid < 64) scnt[tid] = 0;
  sg[wid][lane] = g;
  __syncthreads();
  if (lane == 0) {
    idx[t]  = mi;
    gval[t] = 1.0f / denom;             // gate of argmax: exp(0)/denom
    atomicAdd(&scnt[mi], 1);
  }
  __syncthreads();
  if (tid < 64) {
    atomicAdd(&esum[tid], sg[0][tid] + sg[1][tid] + sg[2][tid] + sg[3][tid]);
    const int c = scnt[tid];
    if (c) atomicAdd(&ecnt[tid], c);
  }
}

// ---------------------------------------------------------------------------
// Per-expert queue positions: pos[t] = rank of token t among tokens routed to
// idx[t] (token order), or -1 if rank >= CAP.  One block per expert.
// ---------------------------------------------------------------------------
__global__ __launch_bounds__(256) void scan_pos(
    const int* __restrict__ idx, int* __restrict__ pos) {
  const int e    = blockIdx.x;
  const int tid  = threadIdx.x;
  const int wid  = tid >> 6;
  const int lane = tid & 63;
  __shared__ int wtot[4];
  __shared__ int carry;
  if (tid == 0) carry = 0;
  __syncthreads();
  for (int base = 0; base < T_TOK; base += 256) {
    const int t    = base + tid;
    const int flag = (idx[t] == e) ? 1 : 0;
    const unsigned long long mask = __ballot(flag);
    const int prefix = __popcll(mask & ((1ull << lane) - 1ull));
    if (lane == 0) wtot[wid] = __popcll(mask);
    __syncthreads();
    int woff = 0;
    for (int w = 0; w < wid; ++w) woff += wtot[w];
    const int p = carry + woff + prefix;
    if (flag) pos[t] = (p < CAP) ? p : -1;
    __syncthreads();
    if (tid == 0) carry += wtot[0] + wtot[1] + wtot[2] + wtot[3];
    __syncthreads();
  }
}

// ---------------------------------------------------------------------------
// Scatter nonzeros into combine / dispatch_mask.
// ---------------------------------------------------------------------------
__global__ __launch_bounds__(256) void scatter(
    const int* __restrict__ idx, const float* __restrict__ gval,
    const int* __restrict__ pos, float* __restrict__ out) {
  const int t = blockIdx.x * 256 + threadIdx.x;
  if (t >= T_TOK) return;
  const int p = pos[t];
  if (p >= 0) {
    const size_t off = ((size_t)t * NEXP + idx[t]) * CAP + p;
    out[1 + off] = gval[t];
    out[1 + (size_t)T_TOK * NEXP * CAP + off] = 1.0f;
  }
}

// ---------------------------------------------------------------------------
// l_aux = E * sum_e(esum[e]*ecnt[e]) / T^2
// ---------------------------------------------------------------------------
__global__ __launch_bounds__(64) void laux_kernel(
    const float* __restrict__ esum, const int* __restrict__ ecnt,
    float* __restrict__ out) {
  const int lane = threadIdx.x;
  float p = esum[lane] * (float)ecnt[lane];
#pragma unroll
  for (int d = 32; d >= 1; d >>= 1) p += __shfl_xor(p, d);
  if (lane == 0)
    out[0] = p * (float)NEXP / ((float)T_TOK * (float)T_TOK);
}

extern "C" void kernel_launch(void* const* d_in, const int* in_sizes, int n_in,
                              void* d_out, int out_size, void* d_ws, size_t ws_size,
                              hipStream_t stream) {
  const float* x  = (const float*)d_in[0];
  const float* wg = (const float*)d_in[1];
  float* out = (float*)d_out;

  // ws layout
  float* part = (float*)d_ws;                              // KSPLIT*T*E floats
  const size_t partN = (size_t)KSPLIT * T_TOK * NEXP;
  int*   idx  = (int*)(part + partN);                      // T ints
  float* gval = (float*)(idx + T_TOK);                     // T floats
  int*   pos  = (int*)(gval + T_TOK);                      // T ints
  float* esum = (float*)(pos + T_TOK);                     // E floats
  int*   ecnt = (int*)(esum + NEXP);                       // E ints

  hipMemsetAsync(d_out, 0, (size_t)out_size * sizeof(float), stream);
  hipMemsetAsync(esum, 0, NEXP * sizeof(float) + NEXP * sizeof(int), stream);

  gemm_partial<<<dim3(T_TOK / 64, KSPLIT), 256, 0, stream>>>(x, wg, part);
  softmax_stats<<<T_TOK / 4, 256, 0, stream>>>(part, idx, gval, esum, ecnt);
  scan_pos<<<NEXP, 256, 0, stream>>>(idx, pos);
  scatter<<<T_TOK / 256, 256, 0, stream>>>(idx, gval, pos, out);
  laux_kernel<<<1, 64, 0, stream>>>(esum, ecnt, out);
}

// Round 2
// 219.887 us; speedup vs baseline: 1.0714x; 1.0714x over previous
//
#include <hip/hip_runtime.h>
#include <cstdint>
#include <cstddef>

#define T_TOK 8192
#define MDIM  4096
#define NEXP  64
#define CAP   128
#define TEC   ((size_t)T_TOK * NEXP * CAP)       // 67,108,864
#define OUTN  ((size_t)(1 + 2 * TEC))            // 134,217,729 floats

// ---------------------------------------------------------------------------
// Fused: split-K GEMM partials (logits) + zero-fill of d_out.
// Role by blockIdx.x % 3: {0,1} -> GEMM tile, {2} -> fill slice.
// GEMM: BM=64 tokens x BN=64 experts x BK=32, 256 thr, 4x4 microtile,
// register prefetch of next K-slab issued before the compute loop.
// ---------------------------------------------------------------------------
__global__ __launch_bounds__(256) void gemm_fill(
    const float* __restrict__ x, const float* __restrict__ wg,
    float* __restrict__ part, float* __restrict__ out,
    float* __restrict__ esum, int ksplit, int nfill) {
  __shared__ __align__(16) float As[32][64];  // [k][m]
  __shared__ __align__(16) float Bs[32][64];  // [k][e]
  const int bid = blockIdx.x;
  const int tid = threadIdx.x;

  if (bid % 3 == 2) {            // ---- fill role: pure HBM write ----
    const int fb = bid / 3;
    const float4 z = make_float4(0.f, 0.f, 0.f, 0.f);
    float4* o4 = (float4*)out;
    const int total4 = (int)((OUTN - 1) / 4);   // 33,554,432
    const int stride = nfill * 256;
    for (int i = fb * 256 + tid; i < total4; i += stride) o4[i] = z;
    if (fb == 0) {
      if (tid == 0) out[OUTN - 1] = 0.f;        // tail element
      if (tid < NEXP) esum[tid] = 0.f;          // zero accumulator for l_aux
    }
    return;
  }

  // ---- GEMM role ----
  const int g      = (bid / 3) * 2 + (bid % 3);   // 0..128*ksplit-1
  const int tile   = g & 127;
  const int ks     = g >> 7;
  const int kchunk = MDIM / ksplit;
  const int niter  = kchunk / 32;
  const int t0     = tile * 64;
  const int kbeg   = ks * kchunk;

  const int tx = tid & 15;         // expert group
  const int ty = tid >> 4;         // token group
  const int r  = tid >> 2;         // staging row (0..63)
  const int q  = tid & 3;          // staging col group

  float acc[4][4] = {};

  const float* xp = x  + (size_t)(t0 + r) * MDIM + kbeg + 8 * q;
  const float* wp = wg + (size_t)r * MDIM + kbeg + 8 * q;
  float4 a0 = *(const float4*)xp, a1 = *(const float4*)(xp + 4);
  float4 b0 = *(const float4*)wp, b1 = *(const float4*)(wp + 4);

  for (int it = 0; it < niter; ++it) {
    __syncthreads();               // WAR: prev compute's LDS reads done
    As[8*q+0][r] = a0.x; As[8*q+1][r] = a0.y; As[8*q+2][r] = a0.z; As[8*q+3][r] = a0.w;
    As[8*q+4][r] = a1.x; As[8*q+5][r] = a1.y; As[8*q+6][r] = a1.z; As[8*q+7][r] = a1.w;
    Bs[8*q+0][r] = b0.x; Bs[8*q+1][r] = b0.y; Bs[8*q+2][r] = b0.z; Bs[8*q+3][r] = b0.w;
    Bs[8*q+4][r] = b1.x; Bs[8*q+5][r] = b1.y; Bs[8*q+6][r] = b1.z; Bs[8*q+7][r] = b1.w;
    __syncthreads();
    if (it + 1 < niter) {          // prefetch next slab; regs a0..b1 are dead
      xp += 32; wp += 32;
      a0 = *(const float4*)xp; a1 = *(const float4*)(xp + 4);
      b0 = *(const float4*)wp; b1 = *(const float4*)(wp + 4);
    }
#pragma unroll
    for (int kk = 0; kk < 32; ++kk) {
      const float4 av = *(const float4*)&As[kk][ty * 4];
      const float4 bv = *(const float4*)&Bs[kk][tx * 4];
      acc[0][0] += av.x * bv.x; acc[0][1] += av.x * bv.y;
      acc[0][2] += av.x * bv.z; acc[0][3] += av.x * bv.w;
      acc[1][0] += av.y * bv.x; acc[1][1] += av.y * bv.y;
      acc[1][2] += av.y * bv.z; acc[1][3] += av.y * bv.w;
      acc[2][0] += av.z * bv.x; acc[2][1] += av.z * bv.y;
      acc[2][2] += av.z * bv.z; acc[2][3] += av.z * bv.w;
      acc[3][0] += av.w * bv.x; acc[3][1] += av.w * bv.y;
      acc[3][2] += av.w * bv.z; acc[3][3] += av.w * bv.w;
    }
  }
#pragma unroll
  for (int i = 0; i < 4; ++i) {
    float4 v = make_float4(acc[i][0], acc[i][1], acc[i][2], acc[i][3]);
    *(float4*)(part + ((size_t)ks * T_TOK + t0 + ty * 4 + i) * NEXP + tx * 4) = v;
  }
}

// ---------------------------------------------------------------------------
// Reduce split-K, softmax + argmax (tie -> min index). 16 tokens per block
// (4 waves x 4 tokens) to cut esum atomic traffic 4x.
// ---------------------------------------------------------------------------
__global__ __launch_bounds__(256) void softmax_stats(
    const float* __restrict__ part, int* __restrict__ idx,
    float* __restrict__ gval, float* __restrict__ esum, int ksplit) {
  const int tid  = threadIdx.x;
  const int wid  = tid >> 6;
  const int lane = tid & 63;

  float gl = 0.f;                       // sum of gate prob for this expert-lane
#pragma unroll
  for (int j = 0; j < 4; ++j) {
    const int t = blockIdx.x * 16 + wid * 4 + j;
    float v = 0.f;
    for (int s = 0; s < ksplit; ++s)
      v += part[((size_t)s * T_TOK + t) * NEXP + lane];
    float m = v; int mi = lane;
#pragma unroll
    for (int d = 32; d >= 1; d >>= 1) {
      const float om = __shfl_xor(m, d);
      const int   oi = __shfl_xor(mi, d);
      if (om > m || (om == m && oi < mi)) { m = om; mi = oi; }
    }
    const float e = expf(v - m);
    float denom = e;
#pragma unroll
    for (int d = 32; d >= 1; d >>= 1) denom += __shfl_xor(denom, d);
    gl += e / denom;
    if (lane == 0) { idx[t] = mi; gval[t] = 1.0f / denom; }
  }

  __shared__ float sg[4][64];
  sg[wid][lane] = gl;
  __syncthreads();
  if (tid < 64)
    atomicAdd(&esum[tid], sg[0][tid] + sg[1][tid] + sg[2][tid] + sg[3][tid]);
}

// ---------------------------------------------------------------------------
// Per-expert scan + scatter + l_aux. idx staged in LDS once; one wave per
// expert (4 experts/block), zero inner barriers; carry is wave-local.
// ---------------------------------------------------------------------------
__global__ __launch_bounds__(256) void scan_scatter(
    const int* __restrict__ idx, const float* __restrict__ gval,
    const float* __restrict__ esum, float* __restrict__ out) {
  __shared__ int sidx[T_TOK];           // 32 KB
  const int tid = threadIdx.x;
  for (int i = tid; i < T_TOK / 4; i += 256)
    ((int4*)sidx)[i] = ((const int4*)idx)[i];
  __syncthreads();

  const int e    = blockIdx.x * 4 + (tid >> 6);
  const int lane = tid & 63;
  int carry = 0;
#pragma unroll 4
  for (int base = 0; base < T_TOK; base += 64) {
    const int t = base + lane;
    const bool flag = (sidx[t] == e);
    const unsigned long long mask = __ballot(flag);
    if (flag) {
      const int p = carry + __popcll(mask & ((1ull << lane) - 1ull));
      if (p < CAP) {
        const size_t off = ((size_t)t * NEXP + e) * CAP + p;
        out[1 + off]       = gval[t];
        out[1 + TEC + off] = 1.0f;
      }
    }
    carry += __popcll(mask);
  }
  if (lane == 0)                        // ce uses pre-drop count = carry
    atomicAdd(out, esum[e] * (float)carry *
                   ((float)NEXP / ((float)T_TOK * (float)T_TOK)));
}

extern "C" void kernel_launch(void* const* d_in, const int* in_sizes, int n_in,
                              void* d_out, int out_size, void* d_ws, size_t ws_size,
                              hipStream_t stream) {
  const float* x  = (const float*)d_in[0];
  const float* wg = (const float*)d_in[1];
  float* out = (float*)d_out;

  // pick split-K by available workspace (part = ksplit*T*E floats)
  const size_t need8 = (size_t)8 * T_TOK * NEXP * 4 + T_TOK * 8 + NEXP * 4;
  const int ksplit = (ws_size >= need8) ? 8 : 4;

  float* part = (float*)d_ws;
  int*   idx  = (int*)(part + (size_t)ksplit * T_TOK * NEXP);
  float* gval = (float*)(idx + T_TOK);
  float* esum = (float*)(gval + T_TOK);

  const int ngemm = 128 * ksplit;
  const int nfill = ngemm / 2;

  gemm_fill<<<ngemm + nfill, 256, 0, stream>>>(x, wg, part, out, esum,
                                               ksplit, nfill);
  softmax_stats<<<T_TOK / 16, 256, 0, stream>>>(part, idx, gval, esum, ksplit);
  scan_scatter<<<NEXP / 4, 256, 0, stream>>>(idx, gval, esum, out);
}